// Round 1
// baseline (100.646 us; speedup 1.0000x reference)
//
#include <hip/hip_runtime.h>

#define ALPHA 0.2f
#define NN 4096
#define IN_DIM 128
#define REPR 64
#define HEADS 8
#define NCOL 640   // 512 numerator + 8 denominator + 120 pad (unused garbage cols)

typedef _Float16 f16;
typedef _Float16 f16x8 __attribute__((ext_vector_type(8)));
typedef float f32x4 __attribute__((ext_vector_type(4)));

union F16x8U { f16 e[8]; f16x8 v; };

// ws layout (bytes)
#define WS_HID 0u            // 8*4096*64*4 = 8388608
#define WS_F2  8388608u      // 8*4096*4 = 131072
#define WS_MX  8519680u      // 32
#define WS_A16 9437184u      // 4096*4096*2 = 33554432
#define WS_MT  45088768u     // 640*4096*2 = 5242880
#define WS_P   50331648u     // 2*4096*640*4 = 20971520
#define WS_END 71303168u

// ---------- k1: hidden[i,j,l] = sum_k node[j,k]*W[i,k,l] (fp32) ----------
__global__ __launch_bounds__(256) void k_hidden(const float* __restrict__ node,
                                                const float* __restrict__ W,
                                                float* __restrict__ hidden) {
  const int i = blockIdx.x;
  const int jb = blockIdx.y * 32;
  __shared__ float nl[32][137];                 // stride 137: conflict-free a-reads
  __shared__ __align__(16) float wl[128][64];
  const int t = threadIdx.x;
  const float4* gn = (const float4*)(node + (size_t)jb * IN_DIM);
  #pragma unroll
  for (int q = 0; q < 4; ++q) {
    int i4 = q * 256 + t;
    int r = i4 >> 5, c4 = i4 & 31;
    float4 v = gn[i4];
    nl[r][c4*4+0] = v.x; nl[r][c4*4+1] = v.y; nl[r][c4*4+2] = v.z; nl[r][c4*4+3] = v.w;
  }
  const float4* gw = (const float4*)(W + (size_t)i * IN_DIM * REPR);
  #pragma unroll
  for (int q = 0; q < 8; ++q) {
    int i4 = q * 256 + t;
    int r = i4 >> 4, c4 = i4 & 15;
    *(float4*)&wl[r][c4*4] = gw[i4];
  }
  __syncthreads();
  const int tx = t & 15, ty = t >> 4;
  float acc0[4] = {0,0,0,0}, acc1[4] = {0,0,0,0};
  #pragma unroll 4
  for (int k = 0; k < 128; ++k) {
    float a0 = nl[2*ty][k], a1 = nl[2*ty+1][k];
    float4 b = *(const float4*)&wl[k][4*tx];
    acc0[0] += a0*b.x; acc0[1] += a0*b.y; acc0[2] += a0*b.z; acc0[3] += a0*b.w;
    acc1[0] += a1*b.x; acc1[1] += a1*b.y; acc1[2] += a1*b.z; acc1[3] += a1*b.w;
  }
  float* o0 = hidden + ((size_t)i*NN + jb + 2*ty) * REPR + 4*tx;
  *(float4*)o0 = make_float4(acc0[0],acc0[1],acc0[2],acc0[3]);
  *(float4*)(o0 + REPR) = make_float4(acc1[0],acc1[1],acc1[2],acc1[3]);
}

// ---------- k2: f2[i,j] = dot(leaky_relu(hidden[i,j,:]), a_dst[i,:]) ----------
__global__ __launch_bounds__(256) void k_f2(const float* __restrict__ hidden,
                                            const float* __restrict__ sa,
                                            float* __restrict__ f2) {
  const int i = blockIdx.x;
  const int j = blockIdx.y * 256 + threadIdx.x;
  const float4* h4 = (const float4*)(hidden + ((size_t)i*NN + j) * REPR);
  const float4* a4 = (const float4*)(sa + i * 2 * REPR + REPR);  // a_dst
  float s = 0.f;
  #pragma unroll
  for (int q = 0; q < 16; ++q) {
    float4 h = h4[q], a = a4[q];
    float x;
    x = h.x; s += (x > 0.f ? x : ALPHA * x) * a.x;
    x = h.y; s += (x > 0.f ? x : ALPHA * x) * a.y;
    x = h.z; s += (x > 0.f ? x : ALPHA * x) * a.z;
    x = h.w; s += (x > 0.f ? x : ALPHA * x) * a.w;
  }
  f2[i*NN + j] = s;
}

// ---------- k3: per-head max of f2 ----------
__global__ __launch_bounds__(256) void k_max(const float* __restrict__ f2,
                                             float* __restrict__ mx) {
  const int i = blockIdx.x, t = threadIdx.x;
  __shared__ float red[256];
  float m = -1e30f;
  #pragma unroll
  for (int q = 0; q < 16; ++q) m = fmaxf(m, f2[i*NN + q*256 + t]);
  red[t] = m; __syncthreads();
  for (int s = 128; s > 0; s >>= 1) {
    if (t < s) red[t] = fmaxf(red[t], red[t + s]);
    __syncthreads();
  }
  if (t == 0) mx[i] = red[0];
}

// ---------- k4: M_T[i*64+l][k] = exp(f2[i,k]-mx[i]) * hidden[i,k,l]  (f16) ----------
__global__ __launch_bounds__(256) void k_mt_num(const float* __restrict__ hidden,
                                                const float* __restrict__ f2,
                                                const float* __restrict__ mx,
                                                f16* __restrict__ MT) {
  const int i = blockIdx.x;
  const int l = threadIdx.x & 63, q = threadIdx.x >> 6;
  const int k0 = blockIdx.y * 32 + q * 8;
  const float m = mx[i];
  float g[8];
  #pragma unroll
  for (int kk = 0; kk < 8; ++kk) g[kk] = __expf(f2[i*NN + k0 + kk] - m);
  F16x8U u;
  #pragma unroll
  for (int kk = 0; kk < 8; ++kk) {
    float h = hidden[((size_t)i*NN + k0 + kk) * REPR + l];
    u.e[kk] = (f16)(g[kk] * h);
  }
  *(f16x8*)&MT[(size_t)(i*REPR + l) * NN + k0] = u.v;
}

// ---------- k4b: M_T[512+i][k] = exp(f2[i,k]-mx[i])  (denominator rows) ----------
__global__ __launch_bounds__(256) void k_mt_den(const float* __restrict__ f2,
                                               const float* __restrict__ mx,
                                               f16* __restrict__ MT) {
  const int gid = blockIdx.x * 256 + threadIdx.x;     // 4096 threads
  const int i = gid >> 9, kq = gid & 511, k0 = kq * 8;
  const float m = mx[i];
  F16x8U u;
  #pragma unroll
  for (int kk = 0; kk < 8; ++kk) u.e[kk] = (f16)__expf(f2[i*NN + k0 + kk] - m);
  *(f16x8*)&MT[(size_t)(512 + i) * NN + k0] = u.v;
}

// ---------- k5: adjacency fp32 -> f16 (0/1 exact) ----------
__global__ __launch_bounds__(256) void k_acvt(const float* __restrict__ A,
                                              f16* __restrict__ A16) {
  const size_t idx = (size_t)blockIdx.x * 256 + threadIdx.x;  // 2M threads x 8 elems
  const float4* a4 = (const float4*)A;
  float4 u = a4[idx*2], w = a4[idx*2+1];
  F16x8U o;
  o.e[0]=(f16)u.x; o.e[1]=(f16)u.y; o.e[2]=(f16)u.z; o.e[3]=(f16)u.w;
  o.e[4]=(f16)w.x; o.e[5]=(f16)w.y; o.e[6]=(f16)w.z; o.e[7]=(f16)w.w;
  *(f16x8*)&A16[idx*8] = o.v;
}

// ---------- k6: P[z][j][c] = sum_{k in split z} A16[j,k] * MT[c,k]  (MFMA f16) ----------
__global__ __launch_bounds__(256) void k_gemm(const f16* __restrict__ A16,
                                              const f16* __restrict__ MT,
                                              float* __restrict__ P) {
  __shared__ __align__(16) f16 smA[128*32];
  __shared__ __align__(16) f16 smB[128*32];
  const int t = threadIdx.x;
  const int lane = t & 63, wid = t >> 6;
  const int c0 = blockIdx.x * 128;
  const int j0 = blockIdx.y * 128;
  const int kz = blockIdx.z * 2048;

  const char* Ab = (const char*)A16;
  const char* Bb = (const char*)MT;
  size_t ga[2], gb[2];
  #pragma unroll
  for (int q = 0; q < 2; ++q) {
    int ci = q*256 + t;
    int m = ci >> 2, sub = ci & 3;          // 4 x 16B chunks per 64B row-slice
    ga[q] = (size_t)(j0 + m) * (NN*2) + (size_t)kz*2 + sub*16;
    gb[q] = (size_t)(c0 + m) * (NN*2) + (size_t)kz*2 + sub*16;
  }
  char* la[2]; char* lb[2];
  #pragma unroll
  for (int q = 0; q < 2; ++q) {
    int cb = (q*256 + wid*64) * 16;         // wave-uniform LDS base
    la[q] = (char*)smA + cb;
    lb[q] = (char*)smB + cb;
  }
  const int frow = lane & 15, kg = lane >> 4;
  const int wr = wid >> 1, wc = wid & 1;
  int aoff[4], boff[4];
  #pragma unroll
  for (int mi = 0; mi < 4; ++mi) aoff[mi] = (wr*64 + mi*16 + frow) * 32 + kg*8;
  #pragma unroll
  for (int ni = 0; ni < 4; ++ni) boff[ni] = (wc*64 + ni*16 + frow) * 32 + kg*8;

  f32x4 acc[4][4] = {};
  for (int kt = 0; kt < 64; ++kt) {
    const size_t kb = (size_t)kt * 64;
    __builtin_amdgcn_global_load_lds((const __attribute__((address_space(1))) void*)(Ab + ga[0] + kb),
                                     (__attribute__((address_space(3))) void*)la[0], 16, 0, 0);
    __builtin_amdgcn_global_load_lds((const __attribute__((address_space(1))) void*)(Ab + ga[1] + kb),
                                     (__attribute__((address_space(3))) void*)la[1], 16, 0, 0);
    __builtin_amdgcn_global_load_lds((const __attribute__((address_space(1))) void*)(Bb + gb[0] + kb),
                                     (__attribute__((address_space(3))) void*)lb[0], 16, 0, 0);
    __builtin_amdgcn_global_load_lds((const __attribute__((address_space(1))) void*)(Bb + gb[1] + kb),
                                     (__attribute__((address_space(3))) void*)lb[1], 16, 0, 0);
    __syncthreads();   // compiler emits vmcnt(0) drain -> LDS ready
    f16x8 a[4], b[4];
    #pragma unroll
    for (int mi = 0; mi < 4; ++mi) a[mi] = *(const f16x8*)&smA[aoff[mi]];
    #pragma unroll
    for (int ni = 0; ni < 4; ++ni) b[ni] = *(const f16x8*)&smB[boff[ni]];
    #pragma unroll
    for (int mi = 0; mi < 4; ++mi)
      #pragma unroll
      for (int ni = 0; ni < 4; ++ni)
        acc[mi][ni] = __builtin_amdgcn_mfma_f32_16x16x32_f16(a[mi], b[ni], acc[mi][ni], 0, 0, 0);
    __syncthreads();   // protect LDS before next stage
  }
  float* Pz = P + (size_t)blockIdx.z * ((size_t)NN * NCOL);
  #pragma unroll
  for (int mi = 0; mi < 4; ++mi) {
    const int orow = j0 + wr*64 + mi*16 + kg*4;
    #pragma unroll
    for (int ni = 0; ni < 4; ++ni) {
      const int ocol = c0 + wc*64 + ni*16 + frow;
      #pragma unroll
      for (int r = 0; r < 4; ++r)
        Pz[(size_t)(orow + r) * NCOL + ocol] = acc[mi][ni][r];
    }
  }
}

// ---------- k7: out[j, i*64+l] = num/den ----------
__global__ __launch_bounds__(256) void k_div(const float* __restrict__ P,
                                             float* __restrict__ out) {
  const int gid = blockIdx.x * 256 + threadIdx.x;   // 2,097,152
  const int j = gid >> 9, c = gid & 511, i = c >> 6;
  const float* P0 = P;
  const float* P1 = P + (size_t)NN * NCOL;
  float num = P0[(size_t)j*NCOL + c] + P1[(size_t)j*NCOL + c];
  float den = P0[(size_t)j*NCOL + 512 + i] + P1[(size_t)j*NCOL + 512 + i];
  out[gid] = num / den;
}

extern "C" void kernel_launch(void* const* d_in, const int* in_sizes, int n_in,
                              void* d_out, int out_size, void* d_ws, size_t ws_size,
                              hipStream_t stream) {
  const float* node = (const float*)d_in[0];
  const float* adj  = (const float*)d_in[1];
  const float* W    = (const float*)d_in[2];
  const float* sa   = (const float*)d_in[3];
  float* out = (float*)d_out;
  char* ws = (char*)d_ws;
  if (ws_size < (size_t)WS_END) return;   // clean failure instead of OOB

  float* hidden = (float*)(ws + WS_HID);
  float* f2     = (float*)(ws + WS_F2);
  float* mx     = (float*)(ws + WS_MX);
  f16*   A16    = (f16*)(ws + WS_A16);
  f16*   MT     = (f16*)(ws + WS_MT);
  float* P      = (float*)(ws + WS_P);

  k_acvt  <<<dim3(8192),      256, 0, stream>>>(adj, A16);
  k_hidden<<<dim3(8, 128),    256, 0, stream>>>(node, W, hidden);
  k_f2    <<<dim3(8, 16),     256, 0, stream>>>(hidden, sa, f2);
  k_max   <<<dim3(8),         256, 0, stream>>>(f2, mx);
  k_mt_num<<<dim3(8, 128),    256, 0, stream>>>(hidden, f2, mx, MT);
  k_mt_den<<<dim3(16),        256, 0, stream>>>(f2, mx, MT);
  k_gemm  <<<dim3(5, 32, 2),  256, 0, stream>>>(A16, MT, P);
  k_div   <<<dim3(8192),      256, 0, stream>>>(P, out);
}

// Round 2
// 88.959 us; speedup vs baseline: 1.1314x; 1.1314x over previous
//
#include <hip/hip_runtime.h>

#define ALPHA 0.2f
#define NN 4096
#define IN_DIM 128
#define REPR 64
#define HEADS 8
#define NCOL 640   // 512 numerator + 8 denominator + 120 pad (unused garbage cols)
#define KSPLIT 3
#define KSEG 1376  // 43 k-steps; last segment 1344 (42 steps)

typedef _Float16 f16;
typedef _Float16 f16x8 __attribute__((ext_vector_type(8)));
typedef float f32x4 __attribute__((ext_vector_type(4)));

union F16x8U { f16 e[8]; f16x8 v; };

// ws layout (bytes) — P overlaps hidden/f2/mx (dead before k_gemm writes P)
#define WS_P   0u            // 3*4096*640*4 = 31457280
#define WS_HID 0u            // 8*4096*64*4 = 8388608 (dead before gemm)
#define WS_F2  8388608u      // 8*4096*4 = 131072    (dead before gemm)
#define WS_MX  8519680u      // 32                   (dead before gemm)
#define WS_A16 31457280u     // 4096*4096*2 = 33554432
#define WS_MT  65011712u     // 640*4096*2 = 5242880
#define WS_END 70254592u     // < 71303168 proven available in R1

#define PPLANE 10485760u     // 4096*640*4 bytes per split-K plane

// ---------- k1: hidden[i,j,l] = sum_k node[j,k]*W[i,k,l] (fp32) ----------
__global__ __launch_bounds__(256) void k_hidden(const float* __restrict__ node,
                                                const float* __restrict__ W,
                                                float* __restrict__ hidden) {
  const int i = blockIdx.x;
  const int jb = blockIdx.y * 32;
  __shared__ float nl[32][137];
  __shared__ __align__(16) float wl[128][64];
  const int t = threadIdx.x;
  const float4* gn = (const float4*)(node + (size_t)jb * IN_DIM);
  #pragma unroll
  for (int q = 0; q < 4; ++q) {
    int i4 = q * 256 + t;
    int r = i4 >> 5, c4 = i4 & 31;
    float4 v = gn[i4];
    nl[r][c4*4+0] = v.x; nl[r][c4*4+1] = v.y; nl[r][c4*4+2] = v.z; nl[r][c4*4+3] = v.w;
  }
  const float4* gw = (const float4*)(W + (size_t)i * IN_DIM * REPR);
  #pragma unroll
  for (int q = 0; q < 8; ++q) {
    int i4 = q * 256 + t;
    int r = i4 >> 4, c4 = i4 & 15;
    *(float4*)&wl[r][c4*4] = gw[i4];
  }
  __syncthreads();
  const int tx = t & 15, ty = t >> 4;
  float acc0[4] = {0,0,0,0}, acc1[4] = {0,0,0,0};
  #pragma unroll 4
  for (int k = 0; k < 128; ++k) {
    float a0 = nl[2*ty][k], a1 = nl[2*ty+1][k];
    float4 b = *(const float4*)&wl[k][4*tx];
    acc0[0] += a0*b.x; acc0[1] += a0*b.y; acc0[2] += a0*b.z; acc0[3] += a0*b.w;
    acc1[0] += a1*b.x; acc1[1] += a1*b.y; acc1[2] += a1*b.z; acc1[3] += a1*b.w;
  }
  float* o0 = hidden + ((size_t)i*NN + jb + 2*ty) * REPR + 4*tx;
  *(float4*)o0 = make_float4(acc0[0],acc0[1],acc0[2],acc0[3]);
  *(float4*)(o0 + REPR) = make_float4(acc1[0],acc1[1],acc1[2],acc1[3]);
}

// ---------- k2: f2[i,j] = dot(leaky_relu(hidden[i,j,:]), a_dst[i,:]) ----------
__global__ __launch_bounds__(256) void k_f2(const float* __restrict__ hidden,
                                            const float* __restrict__ sa,
                                            float* __restrict__ f2) {
  const int i = blockIdx.x;
  const int j = blockIdx.y * 256 + threadIdx.x;
  const float4* h4 = (const float4*)(hidden + ((size_t)i*NN + j) * REPR);
  const float4* a4 = (const float4*)(sa + i * 2 * REPR + REPR);
  float s = 0.f;
  #pragma unroll
  for (int q = 0; q < 16; ++q) {
    float4 h = h4[q], a = a4[q];
    float x;
    x = h.x; s += (x > 0.f ? x : ALPHA * x) * a.x;
    x = h.y; s += (x > 0.f ? x : ALPHA * x) * a.y;
    x = h.z; s += (x > 0.f ? x : ALPHA * x) * a.z;
    x = h.w; s += (x > 0.f ? x : ALPHA * x) * a.w;
  }
  f2[i*NN + j] = s;
}

// ---------- k3: per-head max of f2 ----------
__global__ __launch_bounds__(256) void k_max(const float* __restrict__ f2,
                                             float* __restrict__ mx) {
  const int i = blockIdx.x, t = threadIdx.x;
  __shared__ float red[256];
  float m = -1e30f;
  #pragma unroll
  for (int q = 0; q < 16; ++q) m = fmaxf(m, f2[i*NN + q*256 + t]);
  red[t] = m; __syncthreads();
  for (int s = 128; s > 0; s >>= 1) {
    if (t < s) red[t] = fmaxf(red[t], red[t + s]);
    __syncthreads();
  }
  if (t == 0) mx[i] = red[0];
}

// ---------- k4: M_T[i*64+l][k] = exp(f2[i,k]-mx[i]) * hidden[i,k,l]  (f16) ----------
__global__ __launch_bounds__(256) void k_mt_num(const float* __restrict__ hidden,
                                                const float* __restrict__ f2,
                                                const float* __restrict__ mx,
                                                f16* __restrict__ MT) {
  const int i = blockIdx.x;
  const int l = threadIdx.x & 63, q = threadIdx.x >> 6;
  const int k0 = blockIdx.y * 32 + q * 8;
  const float m = mx[i];
  float g[8];
  #pragma unroll
  for (int kk = 0; kk < 8; ++kk) g[kk] = __expf(f2[i*NN + k0 + kk] - m);
  F16x8U u;
  #pragma unroll
  for (int kk = 0; kk < 8; ++kk) {
    float h = hidden[((size_t)i*NN + k0 + kk) * REPR + l];
    u.e[kk] = (f16)(g[kk] * h);
  }
  *(f16x8*)&MT[(size_t)(i*REPR + l) * NN + k0] = u.v;
}

// ---------- k4b: M_T[512+i][k] = exp(f2[i,k]-mx[i])  (denominator rows) ----------
__global__ __launch_bounds__(256) void k_mt_den(const float* __restrict__ f2,
                                               const float* __restrict__ mx,
                                               f16* __restrict__ MT) {
  const int gid = blockIdx.x * 256 + threadIdx.x;
  const int i = gid >> 9, kq = gid & 511, k0 = kq * 8;
  const float m = mx[i];
  F16x8U u;
  #pragma unroll
  for (int kk = 0; kk < 8; ++kk) u.e[kk] = (f16)__expf(f2[i*NN + k0 + kk] - m);
  *(f16x8*)&MT[(size_t)(512 + i) * NN + k0] = u.v;
}

// ---------- k5: adjacency fp32 -> f16 (0/1 exact) ----------
__global__ __launch_bounds__(256) void k_acvt(const float* __restrict__ A,
                                              f16* __restrict__ A16) {
  const size_t idx = (size_t)blockIdx.x * 256 + threadIdx.x;
  const float4* a4 = (const float4*)A;
  float4 u = a4[idx*2], w = a4[idx*2+1];
  F16x8U o;
  o.e[0]=(f16)u.x; o.e[1]=(f16)u.y; o.e[2]=(f16)u.z; o.e[3]=(f16)u.w;
  o.e[4]=(f16)w.x; o.e[5]=(f16)w.y; o.e[6]=(f16)w.z; o.e[7]=(f16)w.w;
  *(f16x8*)&A16[idx*8] = o.v;
}

// ---------- k6: P[z][j][c] = sum_{k in split z} A16[j,k] * MT[c,k]  (MFMA f16) ----------
// grid = 480 linear blocks; XCD-swizzled so all 15 blocks (5c x 3z) of a
// j-tile land on one XCD -> A row-panel fetched once per XCD.
__global__ __launch_bounds__(256) void k_gemm(const f16* __restrict__ A16,
                                              const f16* __restrict__ MT,
                                              float* __restrict__ P) {
  __shared__ __align__(16) f16 smA[128*32];
  __shared__ __align__(16) f16 smB[128*32];
  const int t = threadIdx.x;
  const int lane = t & 63, wid = t >> 6;

  // --- XCD swizzle: lin -> (c, j, z) with all of a j-tile's work on lin%8 ---
  const int lin = blockIdx.x;                // 0..479
  const int xcd = lin & 7, idx = lin >> 3;   // idx in [0,60)
  const int jt  = xcd + 8 * (idx / 15);      // j-tile 0..31
  const int r   = idx % 15;
  const int ct  = r % 5;                     // c-tile 0..4
  const int zt  = r / 5;                     // K-split 0..2

  const int c0 = ct * 128;
  const int j0 = jt * 128;
  const int kz = zt * KSEG;
  const int nk = (zt == KSPLIT-1 ? (NN - 2*KSEG) : KSEG) / 32;  // 42 or 43

  const char* Ab = (const char*)A16;
  const char* Bb = (const char*)MT;
  size_t ga[2], gb[2];
  #pragma unroll
  for (int q = 0; q < 2; ++q) {
    int ci = q*256 + t;
    int m = ci >> 2, sub = ci & 3;
    ga[q] = (size_t)(j0 + m) * (NN*2) + (size_t)kz*2 + sub*16;
    gb[q] = (size_t)(c0 + m) * (NN*2) + (size_t)kz*2 + sub*16;
  }
  char* la[2]; char* lb[2];
  #pragma unroll
  for (int q = 0; q < 2; ++q) {
    int cb = (q*256 + wid*64) * 16;
    la[q] = (char*)smA + cb;
    lb[q] = (char*)smB + cb;
  }
  const int frow = lane & 15, kg = lane >> 4;
  const int wr = wid >> 1, wc = wid & 1;
  int aoff[4], boff[4];
  #pragma unroll
  for (int mi = 0; mi < 4; ++mi) aoff[mi] = (wr*64 + mi*16 + frow) * 32 + kg*8;
  #pragma unroll
  for (int ni = 0; ni < 4; ++ni) boff[ni] = (wc*64 + ni*16 + frow) * 32 + kg*8;

  f32x4 acc[4][4] = {};
  for (int kt = 0; kt < nk; ++kt) {
    const size_t kb = (size_t)kt * 64;
    __builtin_amdgcn_global_load_lds((const __attribute__((address_space(1))) void*)(Ab + ga[0] + kb),
                                     (__attribute__((address_space(3))) void*)la[0], 16, 0, 0);
    __builtin_amdgcn_global_load_lds((const __attribute__((address_space(1))) void*)(Ab + ga[1] + kb),
                                     (__attribute__((address_space(3))) void*)la[1], 16, 0, 0);
    __builtin_amdgcn_global_load_lds((const __attribute__((address_space(1))) void*)(Bb + gb[0] + kb),
                                     (__attribute__((address_space(3))) void*)lb[0], 16, 0, 0);
    __builtin_amdgcn_global_load_lds((const __attribute__((address_space(1))) void*)(Bb + gb[1] + kb),
                                     (__attribute__((address_space(3))) void*)lb[1], 16, 0, 0);
    __syncthreads();
    f16x8 a[4], b[4];
    #pragma unroll
    for (int mi = 0; mi < 4; ++mi) a[mi] = *(const f16x8*)&smA[aoff[mi]];
    #pragma unroll
    for (int ni = 0; ni < 4; ++ni) b[ni] = *(const f16x8*)&smB[boff[ni]];
    #pragma unroll
    for (int mi = 0; mi < 4; ++mi)
      #pragma unroll
      for (int ni = 0; ni < 4; ++ni)
        acc[mi][ni] = __builtin_amdgcn_mfma_f32_16x16x32_f16(a[mi], b[ni], acc[mi][ni], 0, 0, 0);
    __syncthreads();
  }
  float* Pz = P + (size_t)zt * (PPLANE/4);
  #pragma unroll
  for (int mi = 0; mi < 4; ++mi) {
    const int orow = j0 + wr*64 + mi*16 + kg*4;
    #pragma unroll
    for (int ni = 0; ni < 4; ++ni) {
      const int ocol = c0 + wc*64 + ni*16 + frow;
      #pragma unroll
      for (int r4 = 0; r4 < 4; ++r4)
        Pz[(size_t)(orow + r4) * NCOL + ocol] = acc[mi][ni][r4];
    }
  }
}

// ---------- k7: out[j, i*64+l] = num/den over 3 split-K planes ----------
__global__ __launch_bounds__(256) void k_div(const float* __restrict__ P,
                                             float* __restrict__ out) {
  const int gid = blockIdx.x * 256 + threadIdx.x;   // 2,097,152
  const int j = gid >> 9, c = gid & 511, i = c >> 6;
  const float* P0 = P;
  const float* P1 = P + (size_t)(PPLANE/4);
  const float* P2 = P + (size_t)2*(PPLANE/4);
  const size_t rc = (size_t)j*NCOL + c;
  const size_t rd = (size_t)j*NCOL + 512 + i;
  float num = P0[rc] + P1[rc] + P2[rc];
  float den = P0[rd] + P1[rd] + P2[rd];
  out[gid] = num / den;
}

extern "C" void kernel_launch(void* const* d_in, const int* in_sizes, int n_in,
                              void* d_out, int out_size, void* d_ws, size_t ws_size,
                              hipStream_t stream) {
  const float* node = (const float*)d_in[0];
  const float* adj  = (const float*)d_in[1];
  const float* W    = (const float*)d_in[2];
  const float* sa   = (const float*)d_in[3];
  float* out = (float*)d_out;
  char* ws = (char*)d_ws;
  if (ws_size < (size_t)WS_END) return;

  float* hidden = (float*)(ws + WS_HID);
  float* f2     = (float*)(ws + WS_F2);
  float* mx     = (float*)(ws + WS_MX);
  f16*   A16    = (f16*)(ws + WS_A16);
  f16*   MT     = (f16*)(ws + WS_MT);
  float* P      = (float*)(ws + WS_P);

  k_acvt  <<<dim3(8192),      256, 0, stream>>>(adj, A16);
  k_hidden<<<dim3(8, 128),    256, 0, stream>>>(node, W, hidden);
  k_f2    <<<dim3(8, 16),     256, 0, stream>>>(hidden, sa, f2);
  k_max   <<<dim3(8),         256, 0, stream>>>(f2, mx);
  k_mt_num<<<dim3(8, 128),    256, 0, stream>>>(hidden, f2, mx, MT);
  k_mt_den<<<dim3(16),        256, 0, stream>>>(f2, mx, MT);
  k_gemm  <<<dim3(480),       256, 0, stream>>>(A16, MT, P);
  k_div   <<<dim3(8192),      256, 0, stream>>>(P, out);
}

// Round 3
// 84.086 us; speedup vs baseline: 1.1969x; 1.0579x over previous
//
#include <hip/hip_runtime.h>

#define ALPHA 0.2f
#define NN 4096
#define IN_DIM 128
#define REPR 64
#define HEADS 8
#define NCOL 640   // 512 numerator + 8 denominator + 120 pad (unused garbage cols)
#define KSPLIT 6
#define PLANE_ELEMS (NN * NCOL)

typedef _Float16 f16;
typedef _Float16 f16x8 __attribute__((ext_vector_type(8)));
typedef float f32x4 __attribute__((ext_vector_type(4)));

union F16x8U { f16 e[8]; f16x8 v; };

// ws layout (bytes) — P overlaps hidden/f2/mx (dead before k_gemm writes P)
#define WS_P   0u            // 6*4096*640*2 = 31457280
#define WS_HID 0u            // 8388608 (dead before gemm)
#define WS_F2  8388608u
#define WS_MX  8519680u
#define WS_A16 31457280u     // 4096*4096*2 = 33554432
#define WS_MT  65011712u     // 640*4096*2 = 5242880
#define WS_END 70254592u

// ---------- k1: hidden[i,j,l] = sum_k node[j,k]*W[i,k,l] (fp32) ----------
__global__ __launch_bounds__(256) void k_hidden(const float* __restrict__ node,
                                                const float* __restrict__ W,
                                                float* __restrict__ hidden) {
  const int i = blockIdx.x;
  const int jb = blockIdx.y * 32;
  __shared__ float nl[32][137];
  __shared__ __align__(16) float wl[128][64];
  const int t = threadIdx.x;
  const float4* gn = (const float4*)(node + (size_t)jb * IN_DIM);
  #pragma unroll
  for (int q = 0; q < 4; ++q) {
    int i4 = q * 256 + t;
    int r = i4 >> 5, c4 = i4 & 31;
    float4 v = gn[i4];
    nl[r][c4*4+0] = v.x; nl[r][c4*4+1] = v.y; nl[r][c4*4+2] = v.z; nl[r][c4*4+3] = v.w;
  }
  const float4* gw = (const float4*)(W + (size_t)i * IN_DIM * REPR);
  #pragma unroll
  for (int q = 0; q < 8; ++q) {
    int i4 = q * 256 + t;
    int r = i4 >> 4, c4 = i4 & 15;
    *(float4*)&wl[r][c4*4] = gw[i4];
  }
  __syncthreads();
  const int tx = t & 15, ty = t >> 4;
  float acc0[4] = {0,0,0,0}, acc1[4] = {0,0,0,0};
  #pragma unroll 4
  for (int k = 0; k < 128; ++k) {
    float a0 = nl[2*ty][k], a1 = nl[2*ty+1][k];
    float4 b = *(const float4*)&wl[k][4*tx];
    acc0[0] += a0*b.x; acc0[1] += a0*b.y; acc0[2] += a0*b.z; acc0[3] += a0*b.w;
    acc1[0] += a1*b.x; acc1[1] += a1*b.y; acc1[2] += a1*b.z; acc1[3] += a1*b.w;
  }
  float* o0 = hidden + ((size_t)i*NN + jb + 2*ty) * REPR + 4*tx;
  *(float4*)o0 = make_float4(acc0[0],acc0[1],acc0[2],acc0[3]);
  *(float4*)(o0 + REPR) = make_float4(acc1[0],acc1[1],acc1[2],acc1[3]);
}

// ---------- k2: f2[i,j] = dot(leaky_relu(hidden[i,j,:]), a_dst[i,:]) ----------
__global__ __launch_bounds__(256) void k_f2(const float* __restrict__ hidden,
                                            const float* __restrict__ sa,
                                            float* __restrict__ f2) {
  const int i = blockIdx.x;
  const int j = blockIdx.y * 256 + threadIdx.x;
  const float4* h4 = (const float4*)(hidden + ((size_t)i*NN + j) * REPR);
  const float4* a4 = (const float4*)(sa + i * 2 * REPR + REPR);
  float s = 0.f;
  #pragma unroll
  for (int q = 0; q < 16; ++q) {
    float4 h = h4[q], a = a4[q];
    float x;
    x = h.x; s += (x > 0.f ? x : ALPHA * x) * a.x;
    x = h.y; s += (x > 0.f ? x : ALPHA * x) * a.y;
    x = h.z; s += (x > 0.f ? x : ALPHA * x) * a.z;
    x = h.w; s += (x > 0.f ? x : ALPHA * x) * a.w;
  }
  f2[i*NN + j] = s;
}

// ---------- k3: per-head max of f2 ----------
__global__ __launch_bounds__(256) void k_max(const float* __restrict__ f2,
                                             float* __restrict__ mx) {
  const int i = blockIdx.x, t = threadIdx.x;
  __shared__ float red[256];
  float m = -1e30f;
  #pragma unroll
  for (int q = 0; q < 16; ++q) m = fmaxf(m, f2[i*NN + q*256 + t]);
  red[t] = m; __syncthreads();
  for (int s = 128; s > 0; s >>= 1) {
    if (t < s) red[t] = fmaxf(red[t], red[t + s]);
    __syncthreads();
  }
  if (t == 0) mx[i] = red[0];
}

// ---------- k4: M_T[i*64+l][k] = exp(f2[i,k]-mx[i]) * hidden[i,k,l]  (f16) ----------
__global__ __launch_bounds__(256) void k_mt_num(const float* __restrict__ hidden,
                                                const float* __restrict__ f2,
                                                const float* __restrict__ mx,
                                                f16* __restrict__ MT) {
  const int i = blockIdx.x;
  const int l = threadIdx.x & 63, q = threadIdx.x >> 6;
  const int k0 = blockIdx.y * 32 + q * 8;
  const float m = mx[i];
  float g[8];
  #pragma unroll
  for (int kk = 0; kk < 8; ++kk) g[kk] = __expf(f2[i*NN + k0 + kk] - m);
  F16x8U u;
  #pragma unroll
  for (int kk = 0; kk < 8; ++kk) {
    float h = hidden[((size_t)i*NN + k0 + kk) * REPR + l];
    u.e[kk] = (f16)(g[kk] * h);
  }
  *(f16x8*)&MT[(size_t)(i*REPR + l) * NN + k0] = u.v;
}

// ---------- k4b: M_T[512+i][k] = exp(f2[i,k]-mx[i])  (denominator rows) ----------
__global__ __launch_bounds__(256) void k_mt_den(const float* __restrict__ f2,
                                               const float* __restrict__ mx,
                                               f16* __restrict__ MT) {
  const int gid = blockIdx.x * 256 + threadIdx.x;
  const int i = gid >> 9, kq = gid & 511, k0 = kq * 8;
  const float m = mx[i];
  F16x8U u;
  #pragma unroll
  for (int kk = 0; kk < 8; ++kk) u.e[kk] = (f16)__expf(f2[i*NN + k0 + kk] - m);
  *(f16x8*)&MT[(size_t)(512 + i) * NN + k0] = u.v;
}

// ---------- k5: adjacency fp32 -> f16 (0/1 exact) ----------
__global__ __launch_bounds__(256) void k_acvt(const float* __restrict__ A,
                                              f16* __restrict__ A16) {
  const size_t idx = (size_t)blockIdx.x * 256 + threadIdx.x;
  const float4* a4 = (const float4*)A;
  float4 u = a4[idx*2], w = a4[idx*2+1];
  F16x8U o;
  o.e[0]=(f16)u.x; o.e[1]=(f16)u.y; o.e[2]=(f16)u.z; o.e[3]=(f16)u.w;
  o.e[4]=(f16)w.x; o.e[5]=(f16)w.y; o.e[6]=(f16)w.z; o.e[7]=(f16)w.w;
  *(f16x8*)&A16[idx*8] = o.v;
}

// ---------- k6: P[z][j][c] = sum_{k in split z} A16[j,k] * MT[c,k]  (MFMA f16) ----------
// BK=64; LDS tiles [128 rows][8 slots of 16B], slot-swizzled: global chunk c of
// row m stored at slot c^(m&7) (pre-permuted GLOBAL source, linear LDS dest —
// rule-21-compliant for global_load_lds). Reads XOR the same mask -> 2-way max
// (free). Split-K=6, f16 partials, XCD-swizzled grid (960 = 8*120).
__global__ __launch_bounds__(256) void k_gemm(const f16* __restrict__ A16,
                                              const f16* __restrict__ MT,
                                              f16* __restrict__ P) {
  __shared__ __align__(16) f16 smA[128*64];
  __shared__ __align__(16) f16 smB[128*64];
  const int t = threadIdx.x;
  const int lane = t & 63, wid = t >> 6;

  // --- XCD swizzle: all 30 blocks (5c x 6z) of a j-tile on one XCD ---
  const int lin = blockIdx.x;                // 0..959
  const int xcd = lin & 7, idx = lin >> 3;   // idx in [0,120)
  const int jt  = xcd + 8 * (idx / 30);      // j-tile 0..31
  const int r   = idx % 30;
  const int ct  = r % 5;                     // c-tile 0..4
  const int zt  = r / 5;                     // K-split 0..5

  const int c0 = ct * 128;
  const int j0 = jt * 128;
  // 64 total k-steps of 64: z<4 get 11 steps, z>=4 get 10
  const int nk = (zt < 4) ? 11 : 10;
  const int s0 = zt * 10 + (zt < 4 ? zt : 4);
  const size_t kbase = (size_t)s0 * 128;     // byte offset within a row

  const char* Ab = (const char*)A16;
  const char* Bb = (const char*)MT;
  size_t ga[4], gb[4];
  #pragma unroll
  for (int q = 0; q < 4; ++q) {
    int ci = q*256 + t;                      // chunk 0..1023
    int m = ci >> 3, s = ci & 7;
    int c = s ^ (m & 7);                     // inverse-swizzled source chunk
    ga[q] = (size_t)(j0 + m) * (NN*2) + kbase + (size_t)c*16;
    gb[q] = (size_t)(c0 + m) * (NN*2) + kbase + (size_t)c*16;
  }
  char* la[4]; char* lb[4];
  #pragma unroll
  for (int q = 0; q < 4; ++q) {
    int cb = (q*256 + wid*64) * 16;          // wave-uniform LDS base
    la[q] = (char*)smA + cb;
    lb[q] = (char*)smB + cb;
  }
  const int frow = lane & 15, kg = lane >> 4;
  const int wr = wid >> 1, wc = wid & 1;
  int arow[4], brow[4], soff[2];
  #pragma unroll
  for (int mi = 0; mi < 4; ++mi) arow[mi] = (wr*64 + mi*16 + frow) * 128;
  #pragma unroll
  for (int ni = 0; ni < 4; ++ni) brow[ni] = (wc*64 + ni*16 + frow) * 128;
  #pragma unroll
  for (int kk = 0; kk < 2; ++kk) soff[kk] = ((kk*4 + kg) ^ (frow & 7)) * 16;

  f32x4 acc[4][4] = {};
  for (int kt = 0; kt < nk; ++kt) {
    const size_t kb = (size_t)kt * 128;
    #pragma unroll
    for (int q = 0; q < 4; ++q)
      __builtin_amdgcn_global_load_lds((const __attribute__((address_space(1))) void*)(Ab + ga[q] + kb),
                                       (__attribute__((address_space(3))) void*)la[q], 16, 0, 0);
    #pragma unroll
    for (int q = 0; q < 4; ++q)
      __builtin_amdgcn_global_load_lds((const __attribute__((address_space(1))) void*)(Bb + gb[q] + kb),
                                       (__attribute__((address_space(3))) void*)lb[q], 16, 0, 0);
    __syncthreads();
    #pragma unroll
    for (int kk = 0; kk < 2; ++kk) {
      f16x8 a[4], b[4];
      #pragma unroll
      for (int mi = 0; mi < 4; ++mi) a[mi] = *(const f16x8*)((const char*)smA + arow[mi] + soff[kk]);
      #pragma unroll
      for (int ni = 0; ni < 4; ++ni) b[ni] = *(const f16x8*)((const char*)smB + brow[ni] + soff[kk]);
      #pragma unroll
      for (int mi = 0; mi < 4; ++mi)
        #pragma unroll
        for (int ni = 0; ni < 4; ++ni)
          acc[mi][ni] = __builtin_amdgcn_mfma_f32_16x16x32_f16(a[mi], b[ni], acc[mi][ni], 0, 0, 0);
    }
    __syncthreads();
  }
  f16* Pz = P + (size_t)zt * PLANE_ELEMS;
  #pragma unroll
  for (int mi = 0; mi < 4; ++mi) {
    const int orow = j0 + wr*64 + mi*16 + kg*4;
    #pragma unroll
    for (int ni = 0; ni < 4; ++ni) {
      const int ocol = c0 + wc*64 + ni*16 + frow;
      #pragma unroll
      for (int r4 = 0; r4 < 4; ++r4)
        Pz[(size_t)(orow + r4) * NCOL + ocol] = (f16)acc[mi][ni][r4];
    }
  }
}

// ---------- k7: out[j, i*64+l] = num/den over 6 split-K planes ----------
__global__ __launch_bounds__(256) void k_div(const f16* __restrict__ P,
                                             float* __restrict__ out) {
  const int gid = blockIdx.x * 256 + threadIdx.x;   // 2,097,152
  const int j = gid >> 9, c = gid & 511, i = c >> 6;
  const size_t rc = (size_t)j*NCOL + c;
  const size_t rd = (size_t)j*NCOL + 512 + i;
  float num = 0.f, den = 0.f;
  #pragma unroll
  for (int z = 0; z < KSPLIT; ++z) {
    const f16* Pz = P + (size_t)z * PLANE_ELEMS;
    num += (float)Pz[rc];
    den += (float)Pz[rd];
  }
  out[gid] = num / den;
}

extern "C" void kernel_launch(void* const* d_in, const int* in_sizes, int n_in,
                              void* d_out, int out_size, void* d_ws, size_t ws_size,
                              hipStream_t stream) {
  const float* node = (const float*)d_in[0];
  const float* adj  = (const float*)d_in[1];
  const float* W    = (const float*)d_in[2];
  const float* sa   = (const float*)d_in[3];
  float* out = (float*)d_out;
  char* ws = (char*)d_ws;
  if (ws_size < (size_t)WS_END) return;

  float* hidden = (float*)(ws + WS_HID);
  float* f2     = (float*)(ws + WS_F2);
  float* mx     = (float*)(ws + WS_MX);
  f16*   A16    = (f16*)(ws + WS_A16);
  f16*   MT     = (f16*)(ws + WS_MT);
  f16*   P      = (f16*)(ws + WS_P);

  k_acvt  <<<dim3(8192),      256, 0, stream>>>(adj, A16);
  k_hidden<<<dim3(8, 128),    256, 0, stream>>>(node, W, hidden);
  k_f2    <<<dim3(8, 16),     256, 0, stream>>>(hidden, sa, f2);
  k_max   <<<dim3(8),         256, 0, stream>>>(f2, mx);
  k_mt_num<<<dim3(8, 128),    256, 0, stream>>>(hidden, f2, mx, MT);
  k_mt_den<<<dim3(16),        256, 0, stream>>>(f2, mx, MT);
  k_gemm  <<<dim3(960),       256, 0, stream>>>(A16, MT, P);
  k_div   <<<dim3(8192),      256, 0, stream>>>(P, out);
}